// Round 1
// baseline (1114.732 us; speedup 1.0000x reference)
//
#include <hip/hip_runtime.h>
#include <hip/hip_bf16.h>
#include <cstdint>
#include <cstddef>

typedef __attribute__((ext_vector_type(8))) __bf16 bf16x8;
typedef __attribute__((ext_vector_type(4))) __bf16 bf16x4;
typedef __attribute__((ext_vector_type(4))) float  f32x4;

#define B_  8
#define T_  200
#define U_  100
#define E_  512
#define P_  640
#define H_  512
#define V_  1024

__device__ __forceinline__ void async_ld16(const void* g, void* lds) {
  __builtin_amdgcn_global_load_lds(
      (const __attribute__((address_space(1))) unsigned int*)g,
      (__attribute__((address_space(3))) unsigned int*)lds,
      16, 0, 0);
}

// ---------------- one-launch fp32 -> bf16 convert, 5 segments ----------------
// all segment sizes are exact multiples of 1024 elements (256 thr * 4 elem)
__global__ __launch_bounds__(256)
void cvt_all_kernel(const float* s0, __bf16* d0, const float* s1, __bf16* d1,
                    const float* s2, __bf16* d2, const float* s3, __bf16* d3,
                    const float* s4, __bf16* d4,
                    int e0, int e1, int e2, int e3) {
  int blk = blockIdx.x;
  const float* s; __bf16* d; int base;
  if      (blk < e0) { s = s0; d = d0; base = blk; }
  else if (blk < e1) { s = s1; d = d1; base = blk - e0; }
  else if (blk < e2) { s = s2; d = d2; base = blk - e1; }
  else if (blk < e3) { s = s3; d = d3; base = blk - e2; }
  else               { s = s4; d = d4; base = blk - e3; }
  int i = base * 1024 + threadIdx.x * 4;
  f32x4 v = *(const f32x4*)(s + i);
  bf16x4 o;
  o[0] = (__bf16)v[0]; o[1] = (__bf16)v[1]; o[2] = (__bf16)v[2]; o[3] = (__bf16)v[3];
  *(bf16x4*)(d + i) = o;
}

// ---------------- build joint A (once): joint[m][h] = bf16(relu(enc[bt][h]+pred[b*U+u][h]))
// one wave per m-row, 8 h-elements per lane. grid = 160000/4 blocks of 256.
__global__ __launch_bounds__(256)
void build_joint_kernel(const float* __restrict__ enc, const float* __restrict__ pred,
                        __bf16* __restrict__ out) {
  int m    = blockIdx.x * 4 + (threadIdx.x >> 6);
  int lane = threadIdx.x & 63;
  int h0   = lane * 8;
  int bt = m / U_;
  int u  = m - bt * U_;
  int b  = bt / T_;
  const float* ep = enc  + (size_t)bt * H_ + h0;
  const float* pp = pred + ((size_t)b * U_ + u) * H_ + h0;
  f32x4 e0 = *(const f32x4*)ep, e1 = *(const f32x4*)(ep + 4);
  f32x4 p0 = *(const f32x4*)pp, p1 = *(const f32x4*)(pp + 4);
  bf16x8 q;
#pragma unroll
  for (int i = 0; i < 4; ++i) {
    q[i]     = (__bf16)fmaxf(e0[i] + p0[i], 0.f);
    q[i + 4] = (__bf16)fmaxf(e1[i] + p1[i], 0.f);
  }
  *(bf16x8*)(out + (size_t)m * H_ + h0) = q;
}

// ---------------- generic bf16 GEMM: C[M][ldc] = scale*(A[M][K] * B[N][K]^T + bias) ----
// 256 threads = 4 waves (2x2), tile 128x128, BK=32. A,B staged via global_load_lds.
__global__ __launch_bounds__(256)
void gemm_bias_kernel(const __bf16* __restrict__ A, const __bf16* __restrict__ Bm,
                      const float* __restrict__ bias, float* __restrict__ C,
                      int M, int K, int ldc, float scale) {
  __shared__ __bf16 As[128 * 32];
  __shared__ __bf16 Bs[128 * 32];

  const int tid  = threadIdx.x;
  const int wave = tid >> 6, lane = tid & 63;
  const int l15  = lane & 15, quad = lane >> 4;
  const int wm   = wave & 1,  wn   = wave >> 1;
  const int m0 = blockIdx.y * 128, n0 = blockIdx.x * 128;

  f32x4 acc[4][4];
#pragma unroll
  for (int i = 0; i < 4; ++i)
#pragma unroll
    for (int j = 0; j < 4; ++j) acc[i][j] = (f32x4){0.f, 0.f, 0.f, 0.f};

  for (int kk = 0; kk < K; kk += 32) {
#pragma unroll
    for (int j = 0; j < 2; ++j) {
      int f   = (wave * 2 + j) * 1024 + lane * 16;  // flat byte offset in 8KB tile
      int row = f >> 6;                             // 64B per row (32 bf16)
      int kb  = (f & 63) >> 1;                      // element offset within row
      int ar  = m0 + row; if (ar >= M) ar = M - 1;  // clamp for partial m-tiles
      async_ld16(A  + (size_t)ar * K + kk + kb,        (char*)As + (wave * 2 + j) * 1024);
      async_ld16(Bm + (size_t)(n0 + row) * K + kk + kb,(char*)Bs + (wave * 2 + j) * 1024);
    }
    __syncthreads();
    bf16x8 af[4], bfr[4];
#pragma unroll
    for (int mi = 0; mi < 4; ++mi)
      af[mi] = *(const bf16x8*)(As + (wm * 64 + mi * 16 + l15) * 32 + quad * 8);
#pragma unroll
    for (int ni = 0; ni < 4; ++ni)
      bfr[ni] = *(const bf16x8*)(Bs + (wn * 64 + ni * 16 + l15) * 32 + quad * 8);
#pragma unroll
    for (int mi = 0; mi < 4; ++mi)
#pragma unroll
      for (int ni = 0; ni < 4; ++ni)
        acc[mi][ni] = __builtin_amdgcn_mfma_f32_16x16x32_bf16(af[mi], bfr[ni], acc[mi][ni], 0, 0, 0);
    __syncthreads();
  }

#pragma unroll
  for (int ni = 0; ni < 4; ++ni) {
    int n = n0 + wn * 64 + ni * 16 + l15;
    float bo = bias[n];
#pragma unroll
    for (int mi = 0; mi < 4; ++mi) {
      int mb = m0 + wm * 64 + mi * 16 + quad * 4;
#pragma unroll
      for (int r = 0; r < 4; ++r) {
        int m = mb + r;
        if (m < M) C[(size_t)m * ldc + n] = (acc[mi][ni][r] + bo) * scale;
      }
    }
  }
}

// ---------------- fallback fused joint (used only if workspace too small) ----------------
__global__ __launch_bounds__(256)
void fused_joint_kernel(const float* __restrict__ enc, const float* __restrict__ pred,
                        const __bf16* __restrict__ Wout, const float* __restrict__ b_out,
                        float* __restrict__ out) {
  __shared__ __bf16 As[128 * 40];
  __shared__ __bf16 Bs[128 * 32];

  const int tid  = threadIdx.x;
  const int wave = tid >> 6, lane = tid & 63;
  const int l15  = lane & 15, quad = lane >> 4;
  const int wm   = wave & 1,  wn   = wave >> 1;
  const int n0 = blockIdx.x * 128;
  const int m0 = blockIdx.y * 128;

  const int r   = tid >> 1;
  const int kof = (tid & 1) << 4;
  const int m   = m0 + r;
  const int u   = m % U_;
  const int bt  = m / U_;
  const int b   = bt / T_;
  const float* encp  = enc  + (size_t)bt * H_ + kof;
  const float* predp = pred + ((size_t)b * U_ + u) * H_ + kof;
  __bf16* asp = As + r * 40 + kof;

  f32x4 acc[4][4];
#pragma unroll
  for (int i = 0; i < 4; ++i)
#pragma unroll
    for (int j = 0; j < 4; ++j) acc[i][j] = (f32x4){0.f, 0.f, 0.f, 0.f};

  for (int kk = 0; kk < H_; kk += 32) {
#pragma unroll
    for (int j = 0; j < 2; ++j) {
      int f   = (wave * 2 + j) * 1024 + lane * 16;
      int row = f >> 6;
      int kb  = (f & 63) >> 1;
      async_ld16(Wout + (size_t)(n0 + row) * H_ + kk + kb, (char*)Bs + (wave * 2 + j) * 1024);
    }
    f32x4 ef[4], pf[4];
#pragma unroll
    for (int i = 0; i < 4; ++i) {
      ef[i] = *(const f32x4*)(encp  + kk + i * 4);
      pf[i] = *(const f32x4*)(predp + kk + i * 4);
    }
    bf16x8 q0, q1;
#pragma unroll
    for (int i = 0; i < 8; ++i) {
      float v0 = fmaxf(ef[i >> 2][i & 3] + pf[i >> 2][i & 3], 0.f);
      float v1 = fmaxf(ef[(i + 8) >> 2][(i + 8) & 3] + pf[(i + 8) >> 2][(i + 8) & 3], 0.f);
      q0[i] = (__bf16)v0;
      q1[i] = (__bf16)v1;
    }
    *(bf16x8*)asp       = q0;
    *((bf16x8*)asp + 1) = q1;
    __syncthreads();

    bf16x8 af[4], bfr[4];
#pragma unroll
    for (int mi = 0; mi < 4; ++mi)
      af[mi] = *(const bf16x8*)(As + (wm * 64 + mi * 16 + l15) * 40 + quad * 8);
#pragma unroll
    for (int ni = 0; ni < 4; ++ni)
      bfr[ni] = *(const bf16x8*)(Bs + (wn * 64 + ni * 16 + l15) * 32 + quad * 8);
#pragma unroll
    for (int mi = 0; mi < 4; ++mi)
#pragma unroll
      for (int ni = 0; ni < 4; ++ni)
        acc[mi][ni] = __builtin_amdgcn_mfma_f32_16x16x32_bf16(af[mi], bfr[ni], acc[mi][ni], 0, 0, 0);
    __syncthreads();
  }

#pragma unroll
  for (int ni = 0; ni < 4; ++ni) {
    int n = n0 + wn * 64 + ni * 16 + l15;
    float bo = b_out[n];
#pragma unroll
    for (int mi = 0; mi < 4; ++mi) {
      size_t mb = (size_t)m0 + wm * 64 + mi * 16 + quad * 4;
      float* op = out + mb * V_ + n;
#pragma unroll
      for (int rr = 0; rr < 4; ++rr)
        op[(size_t)rr * V_] = (acc[mi][ni][rr] + bo) * 0.1f;
    }
  }
}

extern "C" void kernel_launch(void* const* d_in, const int* in_sizes, int n_in,
                              void* d_out, int out_size, void* d_ws, size_t ws_size,
                              hipStream_t stream) {
  const float* encoder   = (const float*)d_in[0];  // (8,200,512)
  const float* predictor = (const float*)d_in[1];  // (8,100,640)
  const float* W_enc     = (const float*)d_in[2];  // (512,512)
  const float* b_enc     = (const float*)d_in[3];  // (512,)
  const float* W_pred    = (const float*)d_in[4];  // (512,640)
  const float* b_pred    = (const float*)d_in[5];  // (512,)
  const float* W_out     = (const float*)d_in[6];  // (1024,512)
  const float* b_out     = (const float*)d_in[7];  // (1024,)
  float* out = (float*)d_out;

  char* ws = (char*)d_ws;
  size_t off = 0;
  auto alloc = [&](size_t bytes) { char* p = ws + off; off += (bytes + 255) & ~(size_t)255; return p; };

  float*  enc_f    = (float*)alloc((size_t)1600 * 512 * 4);
  float*  pred_f   = (float*)alloc((size_t)800 * 512 * 4);
  __bf16* enc_bf   = (__bf16*)alloc((size_t)1600 * 512 * 2);
  __bf16* Wenc_bf  = (__bf16*)alloc((size_t)512 * 512 * 2);
  __bf16* pred_bf  = (__bf16*)alloc((size_t)800 * 640 * 2);
  __bf16* Wpred_bf = (__bf16*)alloc((size_t)512 * 640 * 2);
  __bf16* Wout_bf  = (__bf16*)alloc((size_t)1024 * 512 * 2);
  __bf16* joint_bf = (__bf16*)alloc((size_t)160000 * 512 * 2);
  bool big_ws = (off <= ws_size);

  // single-launch convert of all 5 fp32 inputs to bf16
  // segment block counts: enc 800, W_enc 256, pred 500, W_pred 320, W_out 512 (sum 2388)
  cvt_all_kernel<<<2388, 256, 0, stream>>>(
      encoder, enc_bf, W_enc, Wenc_bf, predictor, pred_bf, W_pred, Wpred_bf,
      W_out, Wout_bf, 800, 1056, 1556, 1876);

  // enc = encoder @ W_enc^T + b_enc  -> (1600,512) fp32
  gemm_bias_kernel<<<dim3(4, 13), 256, 0, stream>>>(enc_bf, Wenc_bf, b_enc, enc_f, 1600, 512, 512, 1.0f);
  // pred = predictor @ W_pred^T + b_pred -> (800,512) fp32
  gemm_bias_kernel<<<dim3(4, 7), 256, 0, stream>>>(pred_bf, Wpred_bf, b_pred, pred_f, 800, 640, 512, 1.0f);

  if (big_ws) {
    // materialize joint A once (each element constructed exactly 1x, not 8x)
    build_joint_kernel<<<160000 / 4, 256, 0, stream>>>(enc_f, pred_f, joint_bf);
    // out = 0.1 * (joint @ W_out^T + b_out) as a pure streaming GEMM
    gemm_bias_kernel<<<dim3(8, 1250), 256, 0, stream>>>(joint_bf, Wout_bf, b_out, out,
                                                        160000, 512, 1024, 0.1f);
  } else {
    fused_joint_kernel<<<dim3(8, 1250), 256, 0, stream>>>(enc_f, pred_f, Wout_bf, b_out, out);
  }
}

// Round 2
// 895.711 us; speedup vs baseline: 1.2445x; 1.2445x over previous
//
#include <hip/hip_runtime.h>
#include <hip/hip_bf16.h>
#include <cstdint>
#include <cstddef>

typedef __attribute__((ext_vector_type(8))) __bf16 bf16x8;
typedef __attribute__((ext_vector_type(4))) __bf16 bf16x4;
typedef __attribute__((ext_vector_type(4))) float  f32x4;

#define B_  8
#define T_  200
#define U_  100
#define E_  512
#define P_  640
#define H_  512
#define V_  1024

__device__ __forceinline__ void async_ld16(const void* g, void* lds) {
  __builtin_amdgcn_global_load_lds(
      (const __attribute__((address_space(1))) unsigned int*)g,
      (__attribute__((address_space(3))) unsigned int*)lds,
      16, 0, 0);
}

// ---------------- one-launch fp32 -> bf16 convert, 5 segments ----------------
// all segment sizes are exact multiples of 1024 elements (256 thr * 4 elem)
__global__ __launch_bounds__(256)
void cvt_all_kernel(const float* s0, __bf16* d0, const float* s1, __bf16* d1,
                    const float* s2, __bf16* d2, const float* s3, __bf16* d3,
                    const float* s4, __bf16* d4,
                    int e0, int e1, int e2, int e3) {
  int blk = blockIdx.x;
  const float* s; __bf16* d; int base;
  if      (blk < e0) { s = s0; d = d0; base = blk; }
  else if (blk < e1) { s = s1; d = d1; base = blk - e0; }
  else if (blk < e2) { s = s2; d = d2; base = blk - e1; }
  else if (blk < e3) { s = s3; d = d3; base = blk - e2; }
  else               { s = s4; d = d4; base = blk - e3; }
  int i = base * 1024 + threadIdx.x * 4;
  f32x4 v = *(const f32x4*)(s + i);
  bf16x4 o;
  o[0] = (__bf16)v[0]; o[1] = (__bf16)v[1]; o[2] = (__bf16)v[2]; o[3] = (__bf16)v[3];
  *(bf16x4*)(d + i) = o;
}

// ---------------- dual projection GEMM: z=0 -> enc, z=1 -> pred ----------------
// C[M][512] = A[M][K] * B[N][K]^T + bias. 256 threads = 4 waves (2x2), tile 128x128, BK=32.
__global__ __launch_bounds__(256)
void gemm_dual_kernel(const __bf16* __restrict__ A0, const __bf16* __restrict__ B0,
                      const float* __restrict__ bias0, float* __restrict__ C0, int M0, int K0,
                      const __bf16* __restrict__ A1, const __bf16* __restrict__ B1,
                      const float* __restrict__ bias1, float* __restrict__ C1, int M1, int K1,
                      int ytiles1) {
  const __bf16* A;  const __bf16* Bm;  const float* bias;  float* C;  int M, K;
  if (blockIdx.z == 0) { A = A0; Bm = B0; bias = bias0; C = C0; M = M0; K = K0; }
  else {
    if ((int)blockIdx.y >= ytiles1) return;
    A = A1; Bm = B1; bias = bias1; C = C1; M = M1; K = K1;
  }

  __shared__ __bf16 As[128 * 32];
  __shared__ __bf16 Bs[128 * 32];

  const int tid  = threadIdx.x;
  const int wave = tid >> 6, lane = tid & 63;
  const int l15  = lane & 15, quad = lane >> 4;
  const int wm   = wave & 1,  wn   = wave >> 1;
  const int m0 = blockIdx.y * 128, n0 = blockIdx.x * 128;

  f32x4 acc[4][4];
#pragma unroll
  for (int i = 0; i < 4; ++i)
#pragma unroll
    for (int j = 0; j < 4; ++j) acc[i][j] = (f32x4){0.f, 0.f, 0.f, 0.f};

  for (int kk = 0; kk < K; kk += 32) {
#pragma unroll
    for (int j = 0; j < 2; ++j) {
      int f   = (wave * 2 + j) * 1024 + lane * 16;  // flat byte offset in 8KB tile
      int row = f >> 6;                             // 64B per row (32 bf16)
      int kb  = (f & 63) >> 1;                      // element offset within row
      int ar  = m0 + row; if (ar >= M) ar = M - 1;  // clamp for partial m-tiles
      async_ld16(A  + (size_t)ar * K + kk + kb,        (char*)As + (wave * 2 + j) * 1024);
      async_ld16(Bm + (size_t)(n0 + row) * K + kk + kb,(char*)Bs + (wave * 2 + j) * 1024);
    }
    __syncthreads();
    bf16x8 af[4], bfr[4];
#pragma unroll
    for (int mi = 0; mi < 4; ++mi)
      af[mi] = *(const bf16x8*)(As + (wm * 64 + mi * 16 + l15) * 32 + quad * 8);
#pragma unroll
    for (int ni = 0; ni < 4; ++ni)
      bfr[ni] = *(const bf16x8*)(Bs + (wn * 64 + ni * 16 + l15) * 32 + quad * 8);
#pragma unroll
    for (int mi = 0; mi < 4; ++mi)
#pragma unroll
      for (int ni = 0; ni < 4; ++ni)
        acc[mi][ni] = __builtin_amdgcn_mfma_f32_16x16x32_bf16(af[mi], bfr[ni], acc[mi][ni], 0, 0, 0);
    __syncthreads();
  }

#pragma unroll
  for (int ni = 0; ni < 4; ++ni) {
    int n = n0 + wn * 64 + ni * 16 + l15;
    float bo = bias[n];
#pragma unroll
    for (int mi = 0; mi < 4; ++mi) {
      int mb = m0 + wm * 64 + mi * 16 + quad * 4;
#pragma unroll
      for (int r = 0; r < 4; ++r) {
        int m = mb + r;
        if (m < M) C[(size_t)m * 512 + n] = acc[mi][ni][r] + bo;
      }
    }
  }
}

// ---------------- fused joint: 128m x 256n tile, 512 threads (8 waves, 2m x 4n) ----------
// out[m][v] = 0.1*(sum_h relu(enc[bt][h]+pred[b*U+u][h]) * Wout[v][h] + b_out[v])
// A-tile built in VALU once per block (x4 redundancy across n-blocks, was x8).
// MFMA operand-swap: acc = mfma(B_frag, A_frag) -> thread holds 4 consecutive n
// -> vectorized dwordx4 stores.
__global__ __launch_bounds__(512, 4)
void fused_joint256_kernel(const float* __restrict__ enc, const float* __restrict__ pred,
                           const __bf16* __restrict__ Wout, const float* __restrict__ b_out,
                           float* __restrict__ out) {
  __shared__ __bf16 As[128 * 40];   // padded stride 40 (ds_write'd, padding legal)
  __shared__ __bf16 Bs[256 * 32];   // global_load_lds'd -> contiguous (64B rows)

  const int tid  = threadIdx.x;
  const int wave = tid >> 6, lane = tid & 63;
  const int l15  = lane & 15, quad = lane >> 4;
  const int wm   = wave & 1,  wn   = wave >> 1;   // 2 m-waves x 4 n-waves
  const int n0 = blockIdx.x * 256;
  const int m0 = blockIdx.y * 128;

  // A-construction: 4 threads per row, 8 k-elements each
  const int r    = tid >> 2;
  const int kof  = (tid & 3) << 3;
  const int m    = m0 + r;
  const int bt   = m / U_;
  const int u    = m - bt * U_;
  const int b    = bt / T_;
  const float* encp  = enc  + (size_t)bt * H_ + kof;
  const float* predp = pred + ((size_t)b * U_ + u) * H_ + kof;
  __bf16* asp = As + r * 40 + kof;

  f32x4 acc[4][4];  // [ni][mi]
#pragma unroll
  for (int i = 0; i < 4; ++i)
#pragma unroll
    for (int j = 0; j < 4; ++j) acc[i][j] = (f32x4){0.f, 0.f, 0.f, 0.f};

  for (int kk = 0; kk < H_; kk += 32) {
    // B panel: async stage 256x32 bf16 (16KB), 2 rounds of 512x16B
#pragma unroll
    for (int j = 0; j < 2; ++j) {
      int f   = j * 8192 + tid * 16;   // flat byte offset in 16KB tile
      int row = f >> 6;                // 64B per row (32 bf16)
      int kb  = (f & 63) >> 1;
      async_ld16(Wout + (size_t)(n0 + row) * H_ + kk + kb, (char*)Bs + f);
    }
    // A tile: construct relu(enc+pred) -> bf16 -> LDS (overlaps async B loads)
    f32x4 e0 = *(const f32x4*)(encp  + kk);
    f32x4 e1 = *(const f32x4*)(encp  + kk + 4);
    f32x4 p0 = *(const f32x4*)(predp + kk);
    f32x4 p1 = *(const f32x4*)(predp + kk + 4);
    bf16x8 q;
#pragma unroll
    for (int i = 0; i < 4; ++i) {
      q[i]     = (__bf16)fmaxf(e0[i] + p0[i], 0.f);
      q[i + 4] = (__bf16)fmaxf(e1[i] + p1[i], 0.f);
    }
    *(bf16x8*)asp = q;
    __syncthreads();

    bf16x8 af[4], bfr[4];
#pragma unroll
    for (int mi = 0; mi < 4; ++mi)
      af[mi] = *(const bf16x8*)(As + (wm * 64 + mi * 16 + l15) * 40 + quad * 8);
#pragma unroll
    for (int ni = 0; ni < 4; ++ni)
      bfr[ni] = *(const bf16x8*)(Bs + (wn * 64 + ni * 16 + l15) * 32 + quad * 8);
    // swapped operands: D[quad*4+reg (=n)][l15 (=m)]
#pragma unroll
    for (int ni = 0; ni < 4; ++ni)
#pragma unroll
      for (int mi = 0; mi < 4; ++mi)
        acc[ni][mi] = __builtin_amdgcn_mfma_f32_16x16x32_bf16(bfr[ni], af[mi], acc[ni][mi], 0, 0, 0);
    __syncthreads();
  }

  // epilogue: each thread owns 4 consecutive n (quad*4 + reg) for 4 m values (l15-indexed)
#pragma unroll
  for (int ni = 0; ni < 4; ++ni) {
    int nb = n0 + wn * 64 + ni * 16 + quad * 4;
    f32x4 bo = *(const f32x4*)(b_out + nb);
#pragma unroll
    for (int mi = 0; mi < 4; ++mi) {
      int mm = m0 + wm * 64 + mi * 16 + l15;
      f32x4 v;
#pragma unroll
      for (int rr = 0; rr < 4; ++rr) v[rr] = (acc[ni][mi][rr] + bo[rr]) * 0.1f;
      *(f32x4*)(out + (size_t)mm * V_ + nb) = v;
    }
  }
}

extern "C" void kernel_launch(void* const* d_in, const int* in_sizes, int n_in,
                              void* d_out, int out_size, void* d_ws, size_t ws_size,
                              hipStream_t stream) {
  const float* encoder   = (const float*)d_in[0];  // (8,200,512)
  const float* predictor = (const float*)d_in[1];  // (8,100,640)
  const float* W_enc     = (const float*)d_in[2];  // (512,512)
  const float* b_enc     = (const float*)d_in[3];  // (512,)
  const float* W_pred    = (const float*)d_in[4];  // (512,640)
  const float* b_pred    = (const float*)d_in[5];  // (512,)
  const float* W_out     = (const float*)d_in[6];  // (1024,512)
  const float* b_out     = (const float*)d_in[7];  // (1024,)
  float* out = (float*)d_out;

  char* ws = (char*)d_ws;
  size_t off = 0;
  auto alloc = [&](size_t bytes) { char* p = ws + off; off += (bytes + 255) & ~(size_t)255; return p; };

  float*  enc_f    = (float*)alloc((size_t)1600 * 512 * 4);
  float*  pred_f   = (float*)alloc((size_t)800 * 512 * 4);
  __bf16* enc_bf   = (__bf16*)alloc((size_t)1600 * 512 * 2);
  __bf16* Wenc_bf  = (__bf16*)alloc((size_t)512 * 512 * 2);
  __bf16* pred_bf  = (__bf16*)alloc((size_t)800 * 640 * 2);
  __bf16* Wpred_bf = (__bf16*)alloc((size_t)512 * 640 * 2);
  __bf16* Wout_bf  = (__bf16*)alloc((size_t)1024 * 512 * 2);
  (void)ws_size;

  // single-launch convert of all 5 fp32 inputs to bf16
  // segment block counts: enc 800, W_enc 256, pred 500, W_pred 320, W_out 512 (sum 2388)
  cvt_all_kernel<<<2388, 256, 0, stream>>>(
      encoder, enc_bf, W_enc, Wenc_bf, predictor, pred_bf, W_pred, Wpred_bf,
      W_out, Wout_bf, 800, 1056, 1556, 1876);

  // enc = encoder @ W_enc^T + b_enc  -> (1600,512); pred = predictor @ W_pred^T + b_pred -> (800,512)
  gemm_dual_kernel<<<dim3(4, 13, 2), 256, 0, stream>>>(
      enc_bf,  Wenc_bf,  b_enc,  enc_f,  1600, 512,
      pred_bf, Wpred_bf, b_pred, pred_f,  800, 640, 7);

  // fused joint + output projection (128m x 256n tiles)
  fused_joint256_kernel<<<dim3(4, 1250), 512, 0, stream>>>(enc_f, pred_f, Wout_bf, b_out, out);
}